// Round 1
// baseline (184.539 us; speedup 1.0000x reference)
//
#include <hip/hip_runtime.h>
#include <math.h>

#define B_DIM 512
#define C_DIM 8
#define L_DIM 16384

#define NBLK1 2048
#define THREADS1 (NBLK1 * 256)                       // 524288
#define TOTAL_F4 (B_DIM * C_DIM * L_DIM / 4)         // 16777216
#define ITERS1 (TOTAL_F4 / THREADS1)                 // 32

// ws layout (floats):
//  [0, NBLK1)                : k_sum block partials
//  [NBLK1]                   : global mean
//  [2112, 2112 + 1024*44)    : gram data per (batch, half): {sums[8], tri[36]}
#define WS_MEAN_OFF  NBLK1
#define WS_GRAM_OFF  2112

__global__ __launch_bounds__(256) void k_sum(const float4* __restrict__ in,
                                             float* __restrict__ partials) {
  int tid = blockIdx.x * 256 + threadIdx.x;
  float acc = 0.f;
#pragma unroll
  for (int i = 0; i < ITERS1; ++i) {
    float4 v = in[tid + i * THREADS1];
    acc += (v.x + v.y) + (v.z + v.w);
  }
#pragma unroll
  for (int off = 32; off; off >>= 1) acc += __shfl_down(acc, off, 64);
  __shared__ float s[4];
  int lane = threadIdx.x & 63, wv = threadIdx.x >> 6;
  if (lane == 0) s[wv] = acc;
  __syncthreads();
  if (threadIdx.x == 0) partials[blockIdx.x] = (s[0] + s[1]) + (s[2] + s[3]);
}

__global__ __launch_bounds__(256) void k_mean(const float* __restrict__ partials,
                                              float* __restrict__ mean_out) {
  double acc = 0.0;
  for (int i = threadIdx.x; i < NBLK1; i += 256) acc += (double)partials[i];
#pragma unroll
  for (int off = 32; off; off >>= 1) acc += __shfl_down(acc, off, 64);
  __shared__ double s[4];
  int lane = threadIdx.x & 63, wv = threadIdx.x >> 6;
  if (lane == 0) s[wv] = acc;
  __syncthreads();
  if (threadIdx.x == 0) {
    double tot = (s[0] + s[1]) + (s[2] + s[3]);
    mean_out[0] = (float)(tot / (double)(B_DIM * C_DIM * L_DIM));
  }
}

// One block per (batch, half-of-L). 256 threads, 8 float4-iterations.
__global__ __launch_bounds__(256) void k_gram(const float* __restrict__ in,
                                              const float* __restrict__ mean_p,
                                              const float* __restrict__ bias,
                                              float* __restrict__ gram) {
  const int b    = blockIdx.x >> 1;
  const int half = blockIdx.x & 1;
  const float mu = mean_p[0];
  float bias_l[C_DIM];
#pragma unroll
  for (int c = 0; c < C_DIM; ++c) bias_l[c] = bias[c];

  const float* base = in + (size_t)b * (C_DIM * L_DIM) + half * (L_DIM / 2);

  // acc[0..7] = per-channel sums; acc[8 + i*(i+1)/2 + j] = inter(i,j), i>=j
  float acc[44];
#pragma unroll
  for (int k = 0; k < 44; ++k) acc[k] = 0.f;

#pragma unroll
  for (int it = 0; it < 8; ++it) {
    const int l4 = (it * 256 + threadIdx.x) * 4;   // within half (0..8191)
    float4 v[C_DIM];
#pragma unroll
    for (int c = 0; c < C_DIM; ++c)
      v[c] = *reinterpret_cast<const float4*>(base + c * L_DIM + l4);
#pragma unroll
    for (int e = 0; e < 4; ++e) {
      float s[C_DIM];
#pragma unroll
      for (int c = 0; c < C_DIM; ++c) {
        float a = (e == 0) ? v[c].x : (e == 1) ? v[c].y : (e == 2) ? v[c].z : v[c].w;
        float arg = fmaf(500.f, a - mu, bias_l[c]);
        s[c] = 1.f / (1.f + __expf(-arg));
        acc[c] += s[c];
      }
#pragma unroll
      for (int i = 0; i < C_DIM; ++i)
#pragma unroll
        for (int j = 0; j <= i; ++j)
          acc[8 + (i * (i + 1)) / 2 + j] = fmaf(s[i], s[j], acc[8 + (i * (i + 1)) / 2 + j]);
    }
  }

  // block-reduce the 44 accumulators: wave shuffle, then LDS across 4 waves
  const int lane = threadIdx.x & 63, wv = threadIdx.x >> 6;
  __shared__ float red[4][44];
#pragma unroll
  for (int k = 0; k < 44; ++k) {
    float a = acc[k];
#pragma unroll
    for (int off = 32; off; off >>= 1) a += __shfl_down(a, off, 64);
    if (lane == 0) red[wv][k] = a;
  }
  __syncthreads();
  if (threadIdx.x < 44) {
    float r = (red[0][threadIdx.x] + red[1][threadIdx.x]) +
              (red[2][threadIdx.x] + red[3][threadIdx.x]);
    gram[blockIdx.x * 44 + threadIdx.x] = r;
  }
}

__global__ __launch_bounds__(512) void k_final(const float* __restrict__ gram,
                                               const float* __restrict__ target,
                                               const float* __restrict__ w_fc,
                                               const float* __restrict__ b_fc,
                                               float* __restrict__ out) {
  const int b = threadIdx.x;  // 512 threads, one per batch
  float S[C_DIM], T[36];
#pragma unroll
  for (int k = 0; k < C_DIM; ++k)
    S[k] = gram[b * 88 + k] + gram[b * 88 + 44 + k];
#pragma unroll
  for (int k = 0; k < 36; ++k)
    T[k] = gram[b * 88 + 8 + k] + gram[b * 88 + 44 + 8 + k];

  float st = 0.f;
#pragma unroll
  for (int i = 0; i < C_DIM; ++i)
#pragma unroll
    for (int j = 0; j <= i; ++j) {
      float inter = T[(i * (i + 1)) / 2 + j];
      float uni = (S[i] + S[j]) - inter;
      float sim = inter / uni;
      float tm = 100.f * target[b * 64 + i * 8 + j];
      st += fabsf(sim - tm);
    }

  __shared__ float rs[512];
  // pass 1: mean
  rs[b] = st;
  __syncthreads();
  for (int off = 256; off; off >>= 1) {
    if (b < off) rs[b] += rs[b + off];
    __syncthreads();
  }
  const float mean = rs[0] / 512.f;
  __syncthreads();
  // pass 2: variance (biased)
  float d = st - mean;
  rs[b] = d * d;
  __syncthreads();
  for (int off = 256; off; off >>= 1) {
    if (b < off) rs[b] += rs[b + off];
    __syncthreads();
  }
  const float var = rs[0] / 512.f;
  const float stn = (st - mean) * rsqrtf(var + 1e-5f);
#pragma unroll
  for (int k = 0; k < 3; ++k)
    out[b * 3 + k] = fmaf(stn, w_fc[k], b_fc[k]);
}

extern "C" void kernel_launch(void* const* d_in, const int* in_sizes, int n_in,
                              void* d_out, int out_size, void* d_ws, size_t ws_size,
                              hipStream_t stream) {
  const float* attn   = (const float*)d_in[0];
  const float* target = (const float*)d_in[1];
  const float* bias   = (const float*)d_in[2];
  const float* w_fc   = (const float*)d_in[3];
  const float* b_fc   = (const float*)d_in[4];
  float* out = (float*)d_out;
  float* ws  = (float*)d_ws;

  float* partials = ws;
  float* mean_p   = ws + WS_MEAN_OFF;
  float* gram     = ws + WS_GRAM_OFF;

  k_sum<<<NBLK1, 256, 0, stream>>>((const float4*)attn, partials);
  k_mean<<<1, 256, 0, stream>>>(partials, mean_p);
  k_gram<<<B_DIM * 2, 256, 0, stream>>>(attn, mean_p, bias, gram);
  k_final<<<1, 512, 0, stream>>>(gram, target, w_fc, b_fc, out);
}